// Round 3
// baseline (1802.681 us; speedup 1.0000x reference)
//
#include <hip/hip_runtime.h>

typedef __attribute__((ext_vector_type(8))) short short8;
typedef __attribute__((ext_vector_type(4))) short short4v;
typedef __attribute__((ext_vector_type(4))) float floatx4;

#define B_   128
#define D_   512
#define V_   10000
#define T_   20
#define G4   2048
#define VPAD 10112
#define KP2  10240
#define BD   (B_*D_)

__device__ __forceinline__ unsigned short f2b(float x){
  union { float f; unsigned u; } c; c.f = x;
  unsigned u = c.u;
  unsigned r = (u + 0x7fffu + ((u>>16)&1u)) >> 16;
  return (unsigned short)r;
}
__device__ __forceinline__ float sigm(float x){ return 1.0f/(1.0f+__expf(-x)); }

__global__ void k_zero(float* p, int n){
  int i = blockIdx.x*256 + threadIdx.x;
  if (i < n) p[i] = 0.f;
}

// Transpose+convert W_enc (10000x512 fp32) -> Wenc_b [VPAD][512] bf16 (row-major)
// and WencT [512][KP2] bf16 (K-major, zero-padded cols >= V_)
__global__ __launch_bounds__(256) void k_trans(const float* __restrict__ Wenc,
    unsigned short* __restrict__ Wenc_b, unsigned short* __restrict__ WencT){
  __shared__ short T[64*72];
  int tid = threadIdx.x;
  int v0 = blockIdx.x * 64;
  int d0 = blockIdx.y * 64;
  #pragma unroll
  for (int i=0;i<4;i++){
    int s = tid + 256*i;
    int row = s >> 4, fq = s & 15;
    int v = v0 + row, d = d0 + fq*4;
    float4 f = {0.f,0.f,0.f,0.f};
    if (v < V_) f = *(const float4*)(Wenc + (long)v*D_ + d);
    short4v h; h[0]=(short)f2b(f.x); h[1]=(short)f2b(f.y); h[2]=(short)f2b(f.z); h[3]=(short)f2b(f.w);
    *(short4v*)(&T[row*72 + fq*4]) = h;
    if (v < VPAD) *(short4v*)(Wenc_b + (long)v*D_ + d) = h;
  }
  __syncthreads();
  #pragma unroll
  for (int i=0;i<2;i++){
    int s = tid + 256*i;
    int drow = s >> 3, oct = s & 7;
    short8 v8;
    #pragma unroll
    for (int j=0;j<8;j++) v8[j] = T[(oct*8+j)*72 + drow];
    *(short8*)(WencT + (long)(d0+drow)*KP2 + v0 + oct*8) = v8;
  }
}

// dotv[g] = sum_v W_ih0[g][v] * b_enc[v]
__global__ void k_dotv(const float* __restrict__ Wih0, const float* __restrict__ b_enc,
                       float* __restrict__ dotv){
  __shared__ float red[256];
  int g = blockIdx.x;
  const float* row = Wih0 + (long)g*V_;
  float s = 0.f;
  for (int v = threadIdx.x; v < V_; v += 256) s += row[v]*b_enc[v];
  red[threadIdx.x] = s; __syncthreads();
  for (int w = 128; w >= 1; w >>= 1){
    if (threadIdx.x < w) red[threadIdx.x] += red[threadIdx.x+w];
    __syncthreads();
  }
  if (threadIdx.x == 0) dotv[g] = red[0];
}

// Mf32 (2048x512 fp32, atomically accumulated) += W_ih0 @ WencT^T
// 512 blocks; XCD-swizzled so the 4 n-siblings of a (ks,m) pair share b&7.
__global__ __launch_bounds__(256) void k_fold_gemm(const float* __restrict__ A,
                 const unsigned short* __restrict__ BT, float* __restrict__ Mf32){
  __shared__ short At[128*40];
  __shared__ short Bt[128*40];
  int tid = threadIdx.x;
  int b = blockIdx.x;
  int xcd = b & 7, q = b >> 3;
  int bn = q & 3;
  int pr = xcd + 8*(q >> 2);       // 0..127
  int ks = pr >> 4, bm = pr & 15;
  int m0 = bm*128, n0 = bn*128, kb = ks*1280;
  int lane = tid&63, wave = tid>>6, l15 = lane&15, quad = lane>>4;
  int wm = (wave>>1)*64, wn = (wave&1)*64;
  floatx4 acc[4][4];
  #pragma unroll
  for (int i=0;i<4;i++)
    #pragma unroll
    for(int j=0;j<4;j++){ floatx4 z = {0.f,0.f,0.f,0.f}; acc[i][j] = z; }
  for (int it = 0; it < 40; it++){
    int k0 = kb + it*32;
    #pragma unroll
    for (int i=0;i<2;i++){
      int slot = tid + 256*i;
      int row = slot >> 2, oct = slot & 3;
      const float* src = A + (long)(m0+row)*V_ + k0 + oct*8;
      short8 v;
      if (k0 + 32 <= V_){
        float4 f0 = *(const float4*)src;
        float4 f1 = *(const float4*)(src+4);
        v[0]=(short)f2b(f0.x); v[1]=(short)f2b(f0.y); v[2]=(short)f2b(f0.z); v[3]=(short)f2b(f0.w);
        v[4]=(short)f2b(f1.x); v[5]=(short)f2b(f1.y); v[6]=(short)f2b(f1.z); v[7]=(short)f2b(f1.w);
      } else {
        #pragma unroll
        for (int j=0;j<8;j++){
          int kk = k0 + oct*8 + j;
          float x = (kk < V_) ? src[j] : 0.f;
          v[j] = (short)f2b(x);
        }
      }
      *(short8*)(&At[row*40 + oct*8]) = v;
    }
    #pragma unroll
    for (int i=0;i<2;i++){
      int slot = tid + 256*i;
      int row = slot >> 2, oct = slot & 3;
      *(short8*)(&Bt[row*40 + oct*8]) = *(const short8*)(BT + (long)(n0+row)*KP2 + k0 + oct*8);
    }
    __syncthreads();
    short8 af[4], bf[4];
    #pragma unroll
    for (int i=0;i<4;i++){
      af[i] = *(const short8*)(&At[(wm + i*16 + l15)*40 + quad*8]);
      bf[i] = *(const short8*)(&Bt[(wn + i*16 + l15)*40 + quad*8]);
    }
    #pragma unroll
    for (int mi=0;mi<4;mi++)
      #pragma unroll
      for (int ni=0;ni<4;ni++)
        acc[mi][ni] = __builtin_amdgcn_mfma_f32_16x16x32_bf16(af[mi],bf[ni],acc[mi][ni],0,0,0);
    __syncthreads();
  }
  #pragma unroll
  for (int mi=0;mi<4;mi++)
    #pragma unroll
    for (int ni=0;ni<4;ni++){
      int n = n0 + wn + ni*16 + l15;
      #pragma unroll
      for (int r=0;r<4;r++){
        int m = m0 + wm + mi*16 + quad*4 + r;
        atomicAdd(&Mf32[(long)m*D_ + n], acc[mi][ni][r]);
      }
    }
}

// ---------------- persistent LSTM ----------------
__device__ __forceinline__ void gridbar(int* bar){
  __syncthreads();
  if (threadIdx.x == 0){
    __threadfence();
    int g = __hip_atomic_load(bar+1, __ATOMIC_RELAXED, __HIP_MEMORY_SCOPE_AGENT);
    int prev = __hip_atomic_fetch_add(bar, 1, __ATOMIC_ACQ_REL, __HIP_MEMORY_SCOPE_AGENT);
    if (prev == 255){
      __hip_atomic_store(bar, 0, __ATOMIC_RELAXED, __HIP_MEMORY_SCOPE_AGENT);
      __hip_atomic_fetch_add(bar+1, 1, __ATOMIC_RELEASE, __HIP_MEMORY_SCOPE_AGENT);
    } else {
      while (__hip_atomic_load(bar+1, __ATOMIC_ACQUIRE, __HIP_MEMORY_SCOPE_AGENT) == g)
        __builtin_amdgcn_s_sleep(8);
    }
    __threadfence();
  }
  __syncthreads();
}

// One layer-phase: gates(64x16 slice) = ha@WA^T + hb@WB^T + bias; pointwise; h out.
// Block owns batch rows [bh*64,+64) and gate cols {g*512 + j0+jj : g<4, jj<4} (n = g*4+jj).
__device__ __forceinline__ void do_phase(
    const unsigned short* __restrict__ ha, const unsigned short* __restrict__ hb,
    const short* __restrict__ WA, const short* __restrict__ WB,
    const float* __restrict__ bias16,
    float& cval, unsigned short* __restrict__ hout,
    short* __restrict__ Sg, float* __restrict__ ex,
    int bh, int j0, int tid)
{
  int lane = tid&63, w = tid>>6, l15 = lane&15, quad = lane>>4;
  floatx4 accA = {0.f,0.f,0.f,0.f}, accB = {0.f,0.f,0.f,0.f};
  for (int ch=0; ch<2; ch++){
    int kb = ch*256;
    if (ha){
      #pragma unroll
      for (int i=0;i<8;i++){
        int s = tid + 256*i; int row = s>>5, oct = s&31;
        *(short8*)(&Sg[row*264 + oct*8]) =
          *(const short8*)(ha + (size_t)(bh*64+row)*512 + kb + oct*8);
      }
    }
    if (hb){
      #pragma unroll
      for (int i=0;i<8;i++){
        int s = tid + 256*i; int row = s>>5, oct = s&31;
        *(short8*)(&Sg[64*264 + row*264 + oct*8]) =
          *(const short8*)(hb + (size_t)(bh*64+row)*512 + kb + oct*8);
      }
    }
    __syncthreads();
    #pragma unroll
    for (int ks=0; ks<8; ks++){
      int ko = ks*32 + quad*8;
      if (ha){
        short8 a  = *(const short8*)(&Sg[(w*16+l15)*264 + ko]);
        short8 bb = *(const short8*)(&WA[l15*520 + kb + ko]);
        accA = __builtin_amdgcn_mfma_f32_16x16x32_bf16(a, bb, accA, 0,0,0);
      }
      if (hb){
        short8 a  = *(const short8*)(&Sg[64*264 + (w*16+l15)*264 + ko]);
        short8 bb = *(const short8*)(&WB[l15*520 + kb + ko]);
        accB = __builtin_amdgcn_mfma_f32_16x16x32_bf16(a, bb, accB, 0,0,0);
      }
    }
    __syncthreads();
  }
  #pragma unroll
  for (int r=0;r<4;r++) ex[(w*16 + quad*4 + r)*17 + l15] = accA[r] + accB[r];
  __syncthreads();
  int bl = tid>>2, jj = tid&3;
  float g0 = ex[bl*17 + jj]      + bias16[jj];
  float g1 = ex[bl*17 + 4 + jj]  + bias16[4+jj];
  float g2 = ex[bl*17 + 8 + jj]  + bias16[8+jj];
  float g3 = ex[bl*17 + 12 + jj] + bias16[12+jj];
  float ig = sigm(g0), fg = sigm(g1), gt = tanhf(g2), og = sigm(g3);
  float cn = fg*cval + ig*gt;
  cval = cn;
  hout[(size_t)(bh*64+bl)*512 + j0 + jj] = f2b(og*tanhf(cn));
}

__global__ __launch_bounds__(256,1) void k_persist(
    const float* __restrict__ input_, const float* __restrict__ Mf32,
    const float* __restrict__ Whh0, const float* __restrict__ Wih1,
    const float* __restrict__ Whh1,
    const float* __restrict__ b_ih0, const float* __restrict__ b_hh0,
    const float* __restrict__ b_ih1, const float* __restrict__ b_hh1,
    const float* __restrict__ dotv,
    unsigned short* __restrict__ H0, unsigned short* __restrict__ Hs,
    int* __restrict__ bar)
{
  extern __shared__ char smem[];
  short* WL     = (short*)smem;               // 4 mats x [16][520] = 66,560 B
  short* Sg     = (short*)(smem + 66560);     // 2 terms x [64][264] = 67,584 B
  float* bias_s = (float*)(smem + 134144);    // [3][16]
  float* ex     = (float*)Sg;                 // [64][17] overlay (epilogue)

  int tid = threadIdx.x;
  int b   = blockIdx.x;
  int bh  = b >> 7;
  int jg  = b & 127, j0 = jg*4;

  const float* srcs[4] = {Mf32, Whh0, Wih1, Whh1};
  #pragma unroll
  for (int mat=0; mat<4; mat++){
    const float* W = srcs[mat];
    #pragma unroll
    for (int i=0;i<8;i++){
      int s = tid + 256*i;              // 2048: 16 rows x 128 float4
      int r16 = s>>7, f4 = s&127;
      int g = r16>>2, jj = r16&3;
      float4 f = *(const float4*)(W + ((long)(g*512 + j0 + jj))*512 + f4*4);
      short4v h; h[0]=(short)f2b(f.x); h[1]=(short)f2b(f.y); h[2]=(short)f2b(f.z); h[3]=(short)f2b(f.w);
      *(short4v*)(&WL[mat*16*520 + r16*520 + f4*4]) = h;
    }
  }
  if (tid < 16){
    int g = tid>>2, jj = tid&3;
    int gr = g*512 + j0 + jj;
    float ba = b_ih0[gr] + b_hh0[gr];
    bias_s[16+tid] = ba;                 // t=0 layer0 bias
    bias_s[tid]    = ba + dotv[gr];      // folded layer0 bias
    bias_s[32+tid] = b_ih1[gr] + b_hh1[gr];
  }
  { int i = b*256 + tid; H0[i] = f2b(input_[i]); }   // h0 init = input_
  float c0v = 0.f, c1v = 0.f;
  gridbar(bar);

  for (int t=0; t<T_; t++){
    do_phase(t ? Hs + (size_t)(t-1)*BD : nullptr, H0 + (size_t)t*BD,
             WL + 0*16*520, WL + 1*16*520,
             t ? bias_s : bias_s+16,
             c0v, H0 + (size_t)(t+1)*BD, Sg, ex, bh, j0, tid);
    gridbar(bar);
    do_phase(H0 + (size_t)(t+1)*BD, t ? Hs + (size_t)(t-1)*BD : nullptr,
             WL + 2*16*520, WL + 3*16*520, bias_s+32,
             c1v, Hs + (size_t)t*BD, Sg, ex, bh, j0, tid);
    gridbar(bar);
  }
}

// Out = Hs (2560x512 bf16) @ Wenc_b^T (+b_enc) -> fp32 (2560x10000)
__global__ __launch_bounds__(256) void k_out_gemm(
    const unsigned short* __restrict__ Ah,
    const unsigned short* __restrict__ Bw,
    const float* __restrict__ b_enc, float* __restrict__ out)
{
  __shared__ short At[128*40];
  __shared__ short Bt[128*40];
  int tid = threadIdx.x;
  int bm = blockIdx.x % 20, bn = blockIdx.x / 20;
  int m0 = bm*128, n0 = bn*128;
  int lane = tid&63, wave = tid>>6, l15 = lane&15, quad = lane>>4;
  int wm = (wave>>1)*64, wn = (wave&1)*64;
  floatx4 acc[4][4];
  #pragma unroll
  for (int i=0;i<4;i++)
    #pragma unroll
    for(int j=0;j<4;j++){ floatx4 z = {0.f,0.f,0.f,0.f}; acc[i][j] = z; }
  for (int k0=0;k0<512;k0+=32){
    #pragma unroll
    for (int i=0;i<2;i++){
      int cc = tid + 256*i; int row = cc>>2; int ko=(cc&3)*8;
      *(short8*)(&At[row*40+ko]) = *(const short8*)(Ah + (long)(m0+row)*512 + k0+ko);
      *(short8*)(&Bt[row*40+ko]) = *(const short8*)(Bw + (long)(n0+row)*512 + k0+ko);
    }
    __syncthreads();
    short8 af[4], bf[4];
    #pragma unroll
    for (int i=0;i<4;i++){
      af[i] = *(const short8*)(&At[(wm + i*16 + l15)*40 + quad*8]);
      bf[i] = *(const short8*)(&Bt[(wn + i*16 + l15)*40 + quad*8]);
    }
    #pragma unroll
    for (int mi=0;mi<4;mi++)
      #pragma unroll
      for (int ni=0;ni<4;ni++)
        acc[mi][ni] = __builtin_amdgcn_mfma_f32_16x16x32_bf16(af[mi],bf[ni],acc[mi][ni],0,0,0);
    __syncthreads();
  }
  #pragma unroll
  for (int mi=0;mi<4;mi++)
    #pragma unroll
    for (int ni=0;ni<4;ni++){
      int n = n0 + wn + ni*16 + l15;
      if (n < V_){
        float be = b_enc[n];
        #pragma unroll
        for (int r=0;r<4;r++){
          int m = m0 + wm + mi*16 + quad*4 + r;
          out[(long)m*V_ + n] = acc[mi][ni][r] + be;
        }
      }
    }
}

extern "C" void kernel_launch(void* const* d_in, const int* in_sizes, int n_in,
                              void* d_out, int out_size, void* d_ws, size_t ws_size,
                              hipStream_t stream){
  const float* input_ = (const float*)d_in[0];
  const float* W_ih0  = (const float*)d_in[1];
  const float* W_hh0  = (const float*)d_in[2];
  const float* b_ih0  = (const float*)d_in[3];
  const float* b_hh0  = (const float*)d_in[4];
  const float* W_ih1  = (const float*)d_in[5];
  const float* W_hh1  = (const float*)d_in[6];
  const float* b_ih1  = (const float*)d_in[7];
  const float* b_hh1  = (const float*)d_in[8];
  const float* W_enc  = (const float*)d_in[9];
  const float* b_enc  = (const float*)d_in[10];
  float* out = (float*)d_out;

  char* ws = (char*)d_ws;
  size_t off = 0;
  auto alloc = [&](size_t bytes){ void* p = ws + off; off += (bytes + 255) & ~255ull; return p; };
  unsigned short* Wenc_b  = (unsigned short*)alloc((size_t)VPAD*512*2);
  unsigned short* WencT_b = (unsigned short*)alloc((size_t)512*KP2*2);
  float*          Mf32    = (float*)alloc((size_t)G4*512*4);
  unsigned short* H0      = (unsigned short*)alloc((size_t)(T_+1)*BD*2);
  unsigned short* Hs      = (unsigned short*)alloc((size_t)T_*BD*2);
  float*          dotv    = (float*)alloc(2048*4);
  int*            bar     = (int*)alloc(256);

  k_zero<<<(G4*512+255)/256, 256, 0, stream>>>(Mf32, G4*512);
  k_zero<<<1, 256, 0, stream>>>((float*)bar, 8);
  k_trans<<<dim3(KP2/64, 512/64), 256, 0, stream>>>(W_enc, Wenc_b, WencT_b);
  k_fold_gemm<<<512, 256, 0, stream>>>(W_ih0, WencT_b, Mf32);
  k_dotv<<<2048, 256, 0, stream>>>(W_ih0, b_enc, dotv);
  k_persist<<<256, 256, 134336, stream>>>(input_, Mf32, W_hh0, W_ih1, W_hh1,
                                          b_ih0, b_hh0, b_ih1, b_hh1, dotv,
                                          H0, Hs, bar);
  k_out_gemm<<<20*79, 256, 0, stream>>>(Hs, Wenc_b, b_enc, out);
}